// Round 4
// baseline (43.814 us; speedup 1.0000x reference)
//
#include <hip/hip_runtime.h>

#define NN 128
#define CCH 16
#define BB 4
#define HID 128
#define DOUT 128

// ---------------------------------------------------------------------------
// Kernel 0: per (b,c,32-row stripe): coalesced transpose into xT and diagonal
// extraction into xd. All global reads/writes coalesced; LDS tile padded +1.
// ---------------------------------------------------------------------------
__global__ __launch_bounds__(512) void xpose_diag(
    const float* __restrict__ x, float* __restrict__ xT, float* __restrict__ xd)
{
    __shared__ float tile[32][NN + 1];
    const int t  = threadIdx.x;
    const int bid = blockIdx.x;
    const int st = bid & 3;            // stripe: rows q0..q0+31
    const int c  = (bid >> 2) & 15;
    const int b  = bid >> 6;
    const int q0 = st * 32;
    const float* xm = x + ((size_t)(b * CCH + c) << 14);

    // load 32 rows x 128 cols, fully coalesced float4
    #pragma unroll
    for (int pass = 0; pass < 2; ++pass) {
        const int i = (t >> 5) + pass * 16;
        const int m = (t & 31) * 4;
        const float4 v = *reinterpret_cast<const float4*>(&xm[(q0 + i) * NN + m]);
        tile[i][m]     = v.x;
        tile[i][m + 1] = v.y;
        tile[i][m + 2] = v.z;
        tile[i][m + 3] = v.w;
    }
    __syncthreads();

    if (t < 32) xd[(b * CCH + c) * NN + q0 + t] = tile[t][q0 + t];

    // write xT[p][q0..q0+31]: thread t -> p = t>>2, two float4 groups
    float* xTm = xT + ((size_t)(b * CCH + c) << 14);
    const int p = t >> 2;
    #pragma unroll
    for (int g = 0; g < 2; ++g) {
        const int qq = (t & 3) * 8 + g * 4;
        float4 v;
        v.x = tile[qq + 0][p];
        v.y = tile[qq + 1][p];
        v.z = tile[qq + 2][p];
        v.w = tile[qq + 3][p];
        *reinterpret_cast<float4*>(&xTm[p * NN + q0 + qq]) = v;
    }
}

// ---------------------------------------------------------------------------
// Kernel 1: one block = (b, row p), 512 threads. Same structure as round 3
// but ALL global x reads are coalesced: rows of x, rows of xT (= columns),
// contiguous xd (diagonal).
// ---------------------------------------------------------------------------
__global__ __launch_bounds__(512, 4) void fused_rey(
    const float* __restrict__ x, const float* __restrict__ xT,
    const float* __restrict__ xd,
    const float* __restrict__ W1, const float* __restrict__ b1,
    const float* __restrict__ W2, const float* __restrict__ b2,
    const float* __restrict__ Wc, const float* __restrict__ bc,
    float* __restrict__ y)
{
    __shared__ float s_out[CCH][NN];   // 8 KB
    __shared__ float s_part[8][4];

    const int t   = threadIdx.x;
    const int bid = blockIdx.x;
    const int p   = bid & 127;
    const int b   = bid >> 7;
    const int q   = t & 127;
    const int cq  = t >> 7;            // 0..3
    const int wv  = t >> 6;            // 0..7

    const float bb0 = b2[0], bb1 = b2[1];

    // ---- per-thread x loads: 4 channels c = cq + 4j, all coalesced ----
    float x_pp[4], x_pq[4], x_qp[4], x_qq[4];
    #pragma unroll
    for (int j = 0; j < 4; ++j) {
        const int c = cq + 4 * j;
        const size_t mbase = (size_t)(b * CCH + c) << 14;
        x_pq[j] = x [mbase + p * NN + q];      // row p of x
        x_qp[j] = xT[mbase + p * NN + q];      // row p of xT = column p of x
        x_qq[j] = xd[(b * CCH + c) * NN + q];  // contiguous diagonal
        x_pp[j] = xd[(b * CCH + c) * NN + p];  // wave-uniform -> scalar load
    }

    float h0[4], h1[4];
    #pragma unroll
    for (int j = 0; j < 4; ++j) { h0[j] = bb0; h1[j] = bb1; }

    // ---- phase 1: hidden loop, weights via scalar loads ----
    #pragma unroll 4
    for (int k = 0; k < HID; ++k) {
        const float4 w  = reinterpret_cast<const float4*>(W1)[k];
        const float b1k = b1[k];
        const float w20 = W2[k];
        const float w21 = W2[HID + k];
        #pragma unroll
        for (int j = 0; j < 4; ++j) {
            float hd = fmaf(w.x, x_pp[j], b1k);
            hd = fmaf(w.y, x_pq[j], hd);
            hd = fmaf(w.z, x_qp[j], hd);
            hd = fmaf(w.w, x_qq[j], hd);
            hd = fmaxf(hd, 0.f);
            h0[j] = fmaf(w20, hd, h0[j]);
            h1[j] = fmaf(w21, hd, h1[j]);
        }
    }

    // ---- off-diagonal h1 -> LDS; exclude q==p from diag sum ----
    #pragma unroll
    for (int j = 0; j < 4; ++j) {
        const int c = cq + 4 * j;
        s_out[c][q] = h1[j];
        if (q == p) h0[j] = 0.f;
    }

    // ---- diag: wave shuffle-reduce, then cross-wave combine ----
    #pragma unroll
    for (int j = 0; j < 4; ++j) {
        float v = h0[j];
        for (int off = 32; off > 0; off >>= 1)
            v += __shfl_down(v, off, 64);
        if ((t & 63) == 0) s_part[wv][j] = v;
    }
    __syncthreads();
    if (t < 16) {
        const int cq2 = t >> 2, j2 = t & 3;
        const int c2 = cq2 + 4 * j2;
        s_out[c2][p] = (s_part[2 * cq2][j2] + s_part[2 * cq2 + 1][j2])
                       * (1.0f / (NN - 1));
    }
    __syncthreads();

    // ---- phase 2: y[b,d,p,:] = relu(sum_c s_out[c]*Wc[d][c] + bc[d]) ----
    const int lane = t & 63;
    const int m0 = lane * 2;
    float2 r[CCH];
    #pragma unroll
    for (int c = 0; c < CCH; ++c)
        r[c] = *reinterpret_cast<const float2*>(&s_out[c][m0]);

    #pragma unroll
    for (int dd = 0; dd < 16; ++dd) {
        const int d = wv * 16 + dd;            // wave-uniform
        const float bcv = bc[d];               // scalar load
        float2 acc = { bcv, bcv };
        #pragma unroll
        for (int c = 0; c < CCH; ++c) {
            const float wcv = Wc[d * CCH + c]; // scalar load
            acc.x = fmaf(wcv, r[c].x, acc.x);
            acc.y = fmaf(wcv, r[c].y, acc.y);
        }
        acc.x = fmaxf(acc.x, 0.f);
        acc.y = fmaxf(acc.y, 0.f);
        float* yp = y + ((((size_t)(b * DOUT + d)) * NN + p) * NN + m0);
        *reinterpret_cast<float2*>(yp) = acc;
    }
}

extern "C" void kernel_launch(void* const* d_in, const int* in_sizes, int n_in,
                              void* d_out, int out_size, void* d_ws, size_t ws_size,
                              hipStream_t stream) {
    const float* x  = (const float*)d_in[0];
    const float* W1 = (const float*)d_in[1];
    const float* b1 = (const float*)d_in[2];
    const float* W2 = (const float*)d_in[3];
    const float* b2 = (const float*)d_in[4];
    const float* Wc = (const float*)d_in[5];
    const float* bc = (const float*)d_in[6];
    float* y  = (float*)d_out;

    float* xT = (float*)d_ws;                       // 4 MiB
    float* xd = (float*)d_ws + (size_t)BB * CCH * NN * NN;  // +32 KiB

    dim3 g0(BB * CCH * 4);    // 256 blocks
    xpose_diag<<<g0, 512, 0, stream>>>(x, xT, xd);

    dim3 g1(BB * NN);         // 512 blocks
    fused_rey<<<g1, 512, 0, stream>>>(x, xT, xd, W1, b1, W2, b2, Wc, bc, y);
}

// Round 5
// 39.577 us; speedup vs baseline: 1.1071x; 1.1071x over previous
//
#include <hip/hip_runtime.h>

#define NN 128
#define CCH 16
#define BB 4
#define HID 128
#define DOUT 128

typedef float v2f __attribute__((ext_vector_type(2)));

// ---------------------------------------------------------------------------
// Kernel 0: per (b,c,32-row stripe): coalesced transpose into xT and diagonal
// extraction into xd.
// ---------------------------------------------------------------------------
__global__ __launch_bounds__(512) void xpose_diag(
    const float* __restrict__ x, float* __restrict__ xT, float* __restrict__ xd)
{
    __shared__ float tile[32][NN + 1];
    const int t  = threadIdx.x;
    const int bid = blockIdx.x;
    const int st = bid & 3;            // stripe: rows q0..q0+31
    const int c  = (bid >> 2) & 15;
    const int b  = bid >> 6;
    const int q0 = st * 32;
    const float* xm = x + ((size_t)(b * CCH + c) << 14);

    #pragma unroll
    for (int pass = 0; pass < 2; ++pass) {
        const int i = (t >> 5) + pass * 16;
        const int m = (t & 31) * 4;
        const float4 v = *reinterpret_cast<const float4*>(&xm[(q0 + i) * NN + m]);
        tile[i][m]     = v.x;
        tile[i][m + 1] = v.y;
        tile[i][m + 2] = v.z;
        tile[i][m + 3] = v.w;
    }
    __syncthreads();

    if (t < 32) xd[(b * CCH + c) * NN + q0 + t] = tile[t][q0 + t];

    float* xTm = xT + ((size_t)(b * CCH + c) << 14);
    const int p = t >> 2;
    #pragma unroll
    for (int g = 0; g < 2; ++g) {
        const int qq = (t & 3) * 8 + g * 4;
        float4 v;
        v.x = tile[qq + 0][p];
        v.y = tile[qq + 1][p];
        v.z = tile[qq + 2][p];
        v.w = tile[qq + 3][p];
        *reinterpret_cast<float4*>(&xTm[p * NN + q0 + qq]) = v;
    }
}

// ---------------------------------------------------------------------------
// Kernel 1: one block = (b, row p), 512 threads, (512,2) -> VGPR cap 256.
// Thread (cq=t>>7, q=t&127) handles channels c = cq+4j, j=0..3, as two
// float2 pairs -> v_pk_fma_f32. Weights via wave-uniform scalar loads.
// ---------------------------------------------------------------------------
__global__ __launch_bounds__(512, 2) void fused_rey(
    const float* __restrict__ x, const float* __restrict__ xT,
    const float* __restrict__ xd,
    const float* __restrict__ W1, const float* __restrict__ b1,
    const float* __restrict__ W2, const float* __restrict__ b2,
    const float* __restrict__ Wc, const float* __restrict__ bc,
    float* __restrict__ y)
{
    __shared__ float s_out[CCH][NN];   // 8 KB
    __shared__ float s_part[8][4];

    const int t   = threadIdx.x;
    const int bid = blockIdx.x;
    const int p   = bid & 127;
    const int b   = bid >> 7;
    const int q   = t & 127;
    const int cq  = t >> 7;            // 0..3 (uniform per wave)
    const int wv  = t >> 6;            // 0..7

    const float bb0 = b2[0], bb1 = b2[1];

    // ---- per-thread x loads, all coalesced; packed into float2 pairs ----
    v2f x_pp2[2], x_pq2[2], x_qp2[2], x_qq2[2];
    #pragma unroll
    for (int g = 0; g < 2; ++g) {
        #pragma unroll
        for (int e = 0; e < 2; ++e) {
            const int c = cq + 4 * (2 * g + e);
            const size_t mbase = (size_t)(b * CCH + c) << 14;
            x_pq2[g][e] = x [mbase + p * NN + q];
            x_qp2[g][e] = xT[mbase + p * NN + q];
            x_qq2[g][e] = xd[(b * CCH + c) * NN + q];
            x_pp2[g][e] = xd[(b * CCH + c) * NN + p];   // wave-uniform
        }
    }

    v2f h0_2[2], h1_2[2];
    const v2f z2 = { 0.f, 0.f };
    #pragma unroll
    for (int g = 0; g < 2; ++g) {
        h0_2[g] = (v2f){ bb0, bb0 };
        h1_2[g] = (v2f){ bb1, bb1 };
    }

    // ---- phase 1: hidden loop (packed fp32) ----
    #pragma unroll 4
    for (int k = 0; k < HID; ++k) {
        const float4 w  = reinterpret_cast<const float4*>(W1)[k];
        const float b1k = b1[k];
        const v2f wx = { w.x, w.x }, wy = { w.y, w.y };
        const v2f wz = { w.z, w.z }, ww = { w.w, w.w };
        const v2f bk = { b1k, b1k };
        const v2f w20 = { W2[k], W2[k] };
        const v2f w21 = { W2[HID + k], W2[HID + k] };
        #pragma unroll
        for (int g = 0; g < 2; ++g) {
            v2f hd = __builtin_elementwise_fma(wx, x_pp2[g], bk);
            hd = __builtin_elementwise_fma(wy, x_pq2[g], hd);
            hd = __builtin_elementwise_fma(wz, x_qp2[g], hd);
            hd = __builtin_elementwise_fma(ww, x_qq2[g], hd);
            hd = __builtin_elementwise_max(hd, z2);
            h0_2[g] = __builtin_elementwise_fma(w20, hd, h0_2[g]);
            h1_2[g] = __builtin_elementwise_fma(w21, hd, h1_2[g]);
        }
    }

    // ---- off-diagonal h1 -> LDS; exclude q==p from diag sum ----
    float h0s[4];
    #pragma unroll
    for (int g = 0; g < 2; ++g)
        #pragma unroll
        for (int e = 0; e < 2; ++e) {
            const int j = 2 * g + e;
            const int c = cq + 4 * j;
            s_out[c][q] = h1_2[g][e];
            h0s[j] = (q == p) ? 0.f : h0_2[g][e];
        }

    // ---- diag: wave shuffle-reduce, then cross-wave combine ----
    #pragma unroll
    for (int j = 0; j < 4; ++j) {
        float v = h0s[j];
        for (int off = 32; off > 0; off >>= 1)
            v += __shfl_down(v, off, 64);
        if ((t & 63) == 0) s_part[wv][j] = v;
    }
    __syncthreads();
    if (t < 16) {
        const int cq2 = t >> 2, j2 = t & 3;
        const int c2 = cq2 + 4 * j2;
        s_out[c2][p] = (s_part[2 * cq2][j2] + s_part[2 * cq2 + 1][j2])
                       * (1.0f / (NN - 1));
    }
    __syncthreads();

    // ---- phase 2: y[b,d,p,:] = relu(sum_c s_out[c]*Wc[d][c] + bc[d]) ----
    const int lane = t & 63;
    const int m0 = lane * 2;
    v2f r[CCH];
    #pragma unroll
    for (int c = 0; c < CCH; ++c)
        r[c] = *reinterpret_cast<const v2f*>(&s_out[c][m0]);

    #pragma unroll
    for (int dd = 0; dd < 16; ++dd) {
        const int d = wv * 16 + dd;            // wave-uniform
        const float bcv = bc[d];               // scalar load
        v2f acc = { bcv, bcv };
        #pragma unroll
        for (int c = 0; c < CCH; ++c) {
            const float wcf = Wc[d * CCH + c]; // scalar load
            const v2f wcv = { wcf, wcf };
            acc = __builtin_elementwise_fma(wcv, r[c], acc);
        }
        acc = __builtin_elementwise_max(acc, z2);
        float* yp = y + ((((size_t)(b * DOUT + d)) * NN + p) * NN + m0);
        *reinterpret_cast<v2f*>(yp) = acc;
    }
}

extern "C" void kernel_launch(void* const* d_in, const int* in_sizes, int n_in,
                              void* d_out, int out_size, void* d_ws, size_t ws_size,
                              hipStream_t stream) {
    const float* x  = (const float*)d_in[0];
    const float* W1 = (const float*)d_in[1];
    const float* b1 = (const float*)d_in[2];
    const float* W2 = (const float*)d_in[3];
    const float* b2 = (const float*)d_in[4];
    const float* Wc = (const float*)d_in[5];
    const float* bc = (const float*)d_in[6];
    float* y  = (float*)d_out;

    float* xT = (float*)d_ws;                                // 4 MiB
    float* xd = (float*)d_ws + (size_t)BB * CCH * NN * NN;   // +32 KiB

    dim3 g0(BB * CCH * 4);    // 256 blocks
    xpose_diag<<<g0, 512, 0, stream>>>(x, xT, xd);

    dim3 g1(BB * NN);         // 512 blocks, 2 per CU
    fused_rey<<<g1, 512, 0, stream>>>(x, xT, xd, W1, b1, W2, b2, Wc, bc, y);
}